// Round 4
// baseline (753.506 us; speedup 1.0000x reference)
//
#include <hip/hip_runtime.h>
#include <math.h>

#define H 1024
#define SEQ 2048
#define BATCH 8
#define N_ENT 1000
#define TOPK 5
#define LN_EPS 1e-5f

using bf16x8 = __attribute__((ext_vector_type(8))) __bf16;
using f32x4  = __attribute__((ext_vector_type(4))) float;
#define AS1 __attribute__((address_space(1)))
#define AS3 __attribute__((address_space(3)))

// ---------- helpers ----------

// fast erf-GELU: Abramowitz-Stegun 7.1.26, |erf err| <= 1.5e-7, hw rcp/exp2
__device__ __forceinline__ float gelu_fast(float x) {
    float z = fabsf(x) * 0.70710678118654752440f;
    float t = __builtin_amdgcn_rcpf(fmaf(0.3275911f, z, 1.0f));
    float p = fmaf(fmaf(fmaf(fmaf(1.061405429f, t, -1.453152027f), t, 1.421413741f),
                        t, -0.284496736f), t, 0.254829592f) * t;
    float e = __builtin_amdgcn_exp2f(-z * z * 1.44269504088896f);
    float erfz = fmaf(-p, e, 1.0f);
    float s = copysignf(erfz, x);
    return 0.5f * x * (1.0f + s);
}

__device__ __forceinline__ float sigmoidf_(float x) {
    return 1.0f / (1.0f + expf(-x));
}

__device__ __forceinline__ unsigned short f2bf(float f) {
    unsigned int u = __float_as_uint(f);
    unsigned int r = (u + 0x7fffu + ((u >> 16) & 1u)) >> 16;  // RNE
    return (unsigned short)r;
}

__device__ float block_sum(float v, float* red) {
    for (int off = 32; off > 0; off >>= 1) v += __shfl_down(v, off, 64);
    int wid = threadIdx.x >> 6;
    int lane = threadIdx.x & 63;
    int nw = blockDim.x >> 6;
    if (lane == 0) red[wid] = v;
    __syncthreads();
    if (threadIdx.x == 0) {
        float s = 0.f;
        for (int i = 0; i < nw; ++i) s += red[i];
        red[0] = s;
    }
    __syncthreads();
    float r = red[0];
    __syncthreads();
    return r;
}

// ---------- conversion kernels ----------

__global__ void f2bf_kernel(const float* __restrict__ in, unsigned short* __restrict__ out, int n) {
    int i = (blockIdx.x * blockDim.x + threadIdx.x) * 4;
    if (i >= n) return;
    float4 v = *(const float4*)(in + i);
    ushort4 o;
    o.x = f2bf(v.x); o.y = f2bf(v.y); o.z = f2bf(v.z); o.w = f2bf(v.w);
    *(ushort4*)(out + i) = o;
}

// in [R][C] fp32 -> out [C][R] bf16
__global__ void transpose_bf_kernel(const float* __restrict__ in, unsigned short* __restrict__ out,
                                    int R, int C) {
    __shared__ float tile[32][33];
    int c0 = blockIdx.x * 32, r0 = blockIdx.y * 32;
    int tx = threadIdx.x & 31, ty = threadIdx.x >> 5;
#pragma unroll
    for (int i = 0; i < 32; i += 8)
        tile[ty + i][tx] = in[(size_t)(r0 + ty + i) * C + c0 + tx];
    __syncthreads();
#pragma unroll
    for (int i = 0; i < 32; i += 8)
        out[(size_t)(c0 + ty + i) * R + r0 + tx] = f2bf(tile[tx][ty + i]);
}

// ---------- pooling (2-phase) + fused hs->bf16 ----------

__global__ void pool1_kernel(const float* __restrict__ hs, float* __restrict__ part,
                             unsigned short* __restrict__ hsb) {
    int sc = blockIdx.x, b = blockIdx.y, t = threadIdx.x;
    float a0 = 0, a1 = 0, a2 = 0, a3 = 0;
    size_t rowbase = (size_t)b * SEQ + sc * 64;
    const float* p = hs + rowbase * H;
    for (int s = 0; s < 64; ++s) {
        const float* q = p + (size_t)s * H;
        float v0 = q[t], v1 = q[t + 256], v2 = q[t + 512], v3 = q[t + 768];
        a0 += v0; a1 += v1; a2 += v2; a3 += v3;
        if (hsb) {
            unsigned short* w = hsb + (rowbase + s) * H;
            w[t] = f2bf(v0); w[t + 256] = f2bf(v1); w[t + 512] = f2bf(v2); w[t + 768] = f2bf(v3);
        }
    }
    float* o = part + ((size_t)b * 32 + sc) * H;
    o[t] = a0; o[t + 256] = a1; o[t + 512] = a2; o[t + 768] = a3;
}

__global__ void pool2_kernel(const float* __restrict__ part, float* __restrict__ pooled) {
    int b = blockIdx.y, c = blockIdx.x, t = threadIdx.x;
    float s = 0.f;
    for (int sc = 0; sc < 32; ++sc) s += part[((size_t)b * 32 + sc) * H + t + c * 256];
    pooled[b * H + t + c * 256] = s * (1.0f / SEQ);
}

// ---------- small MLP path: full-K fc kernels ----------
// out[b][c] = act( sum_k X[b][k]*W[k][c] + bias[c] ), batch fixed at 8.
// grid N/64, block 256; thread: col c = bid*64+(t&63), k-slice s = t>>6.
template <int K, int ACT>
__global__ __launch_bounds__(256) void fc_kernel(const float* __restrict__ X,
                                                 const float* __restrict__ W,
                                                 const float* __restrict__ bias, int N,
                                                 float* __restrict__ out) {
    __shared__ float xs[8 * K];
    __shared__ float red[4][8][64];
    int t = threadIdx.x;
    for (int i = t; i < 8 * K; i += 256) xs[i] = X[i];
    __syncthreads();
    int cl = t & 63;
    int c = blockIdx.x * 64 + cl;
    int s = t >> 6;
    const int KS = K / 4;
    float acc[8] = {};
#pragma unroll 4
    for (int k = s * KS; k < (s + 1) * KS; ++k) {
        float w = W[(size_t)k * N + c];
#pragma unroll
        for (int b = 0; b < 8; ++b) acc[b] = fmaf(xs[b * K + k], w, acc[b]);
    }
#pragma unroll
    for (int b = 0; b < 8; ++b) red[s][b][cl] = acc[b];
    __syncthreads();
    if (s == 0) {
#pragma unroll
        for (int b = 0; b < 8; ++b) {
            float v = red[0][b][cl] + red[1][b][cl] + red[2][b][cl] + red[3][b][cl] + bias[c];
            if (ACT) v = gelu_fast(v);
            out[(size_t)b * N + c] = v;
        }
    }
}

// LN over H per row.  grid 8, block 1024
__global__ void ln_vec_kernel(const float* __restrict__ in, const float* __restrict__ g,
                              const float* __restrict__ be, float* __restrict__ out) {
    __shared__ float red[32];
    int b = blockIdx.x, t = threadIdx.x;
    float s = in[(size_t)b * H + t];
    float mu = block_sum(s, red) * (1.0f / H);
    float d = s - mu;
    float var = block_sum(d * d, red) * (1.0f / H);
    out[(size_t)b * H + t] = d * rsqrtf(var + LN_EPS) * g[t] + be[t];
}

// ---------- sims / topk / gather+concat / validation tail ----------

__global__ void sim_kernel(const float* __restrict__ rel, const float* __restrict__ ent,
                           float* __restrict__ sims) {
    __shared__ float rl[8 * H];
    int t = threadIdx.x;
    for (int i = t; i < 8 * H; i += 256) rl[i] = rel[i];
    __syncthreads();
    int e = blockIdx.x * 4 + (t >> 6);
    int lane = t & 63;
    float ev[16];
    const float* ep = ent + (size_t)e * H;
#pragma unroll
    for (int i = 0; i < 16; ++i) ev[i] = ep[lane + i * 64];
#pragma unroll
    for (int b = 0; b < 8; ++b) {
        float a = 0.f;
#pragma unroll
        for (int i = 0; i < 16; ++i) a = fmaf(ev[i], rl[b * H + lane + i * 64], a);
        for (int off = 32; off > 0; off >>= 1) a += __shfl_down(a, off, 64);
        if (lane == 0) sims[b * N_ENT + e] = a;
    }
}

__global__ void topk_kernel(const float* __restrict__ sims, float* __restrict__ out_idx_f,
                            int* __restrict__ idx_i) {
    __shared__ float v[1024];
    __shared__ float rv[4];
    __shared__ int ri[4];
    int b = blockIdx.x, t = threadIdx.x;
    for (int i = t; i < 1024; i += 256) v[i] = (i < N_ENT) ? sims[b * N_ENT + i] : -INFINITY;
    __syncthreads();
    for (int k = 0; k < TOPK; ++k) {
        float best = -INFINITY;
        int bi = 0x7fffffff;
        for (int i = t; i < 1024; i += 256) {
            float x = v[i];
            if (x > best || (x == best && i < bi)) { best = x; bi = i; }
        }
        for (int off = 32; off > 0; off >>= 1) {
            float ov = __shfl_down(best, off, 64);
            int oi = __shfl_down(bi, off, 64);
            if (ov > best || (ov == best && oi < bi)) { best = ov; bi = oi; }
        }
        if ((t & 63) == 0) { rv[t >> 6] = best; ri[t >> 6] = bi; }
        __syncthreads();
        if (t == 0) {
            for (int w = 1; w < 4; ++w)
                if (rv[w] > rv[0] || (rv[w] == rv[0] && ri[w] < ri[0])) { rv[0] = rv[w]; ri[0] = ri[w]; }
            int sel = ri[0];
            out_idx_f[b * TOPK + k] = (float)sel;
            idx_i[b * TOPK + k] = sel;
            v[sel] = -INFINITY;
        }
        __syncthreads();
    }
}

__global__ void gather_concat_kernel(const float* __restrict__ ent, const int* __restrict__ idx,
                                     const float* __restrict__ rel, const float* __restrict__ pooled,
                                     float* __restrict__ retrieved, float* __restrict__ xin) {
    int b = blockIdx.x, h = threadIdx.x;
    float acc = 0.f;
    for (int k = 0; k < TOPK; ++k) {
        float v = ent[(size_t)idx[b * TOPK + k] * H + h];
        retrieved[((size_t)b * TOPK + k) * H + h] = v;
        acc += v;
    }
    float* xb = xin + (size_t)b * 3 * H;
    xb[h] = acc * (1.0f / TOPK);
    xb[H + h] = rel[b * H + h];
    xb[2 * H + h] = pooled[b * H + h];
}

// h already gelu'd [8][512]; dot with w2 + sigmoid.  grid 8, block 512
__global__ void vn_final_kernel(const float* __restrict__ h, const float* __restrict__ w2,
                                const float* __restrict__ b2, float* __restrict__ vs) {
    __shared__ float red[32];
    int b = blockIdx.x, t = threadIdx.x;
    float c = h[(size_t)b * 512 + t] * w2[t];
    float tot = block_sum(c, red);
    if (t == 0) vs[b] = sigmoidf_(tot + b2[0]);
}

// ---------- bf16 MFMA GEMM ----------
// 128x128 tile, BK=32, double-buffered LDS (single barrier/iter),
// XCD-aligned group swizzle (GROUP_M=8: block->XCD is %8 round-robin, so each
// XCD keeps ONE 256KB A-panel L2-resident across all n-panels).
template <int GELU_BF16_OUT>
__global__ __launch_bounds__(256) void gemm_mfma(const unsigned short* __restrict__ A,
                                                 const unsigned short* __restrict__ Bt,
                                                 const float* __restrict__ bias,
                                                 void* __restrict__ Cout,
                                                 int M, int N, int K) {
    __shared__ __align__(16) unsigned short As[2][128 * 32];
    __shared__ __align__(16) unsigned short Bs[2][128 * 32];
    const int tid = threadIdx.x;
    const int lane = tid & 63;

    const int Mp = M >> 7, Np = N >> 7;
    const int GM = 8;
    int per_group = GM * Np;
    int group = blockIdx.x / per_group;
    int rem = blockIdx.x - group * per_group;
    int gbase = group * GM;
    int gm = Mp - gbase; if (gm > GM) gm = GM;
    const int m0 = (gbase + rem % gm) * 128;
    const int n0 = (rem / gm) * 128;

    const int wave = tid >> 6;
    const int wm = (wave >> 1) * 64, wn = (wave & 1) * 64;
    const int rowA_f = wm + (lane & 15);
    const int rowB_f = wn + (lane & 15);
    const int kq = (lane >> 4) * 8;

    auto stage = [&](int kbase, int buf) {
#pragma unroll
        for (int r = 0; r < 2; ++r) {
            int e = (r * 256 + tid) * 8;
            int row = e >> 5, kk = e & 31;
            const unsigned short* ga = A + (size_t)(m0 + row) * K + kbase + kk;
            const unsigned short* gb = Bt + (size_t)(n0 + row) * K + kbase + kk;
            unsigned short* la = &As[buf][(size_t)(r * 256 + (tid & ~63)) * 8];
            unsigned short* lb = &Bs[buf][(size_t)(r * 256 + (tid & ~63)) * 8];
            __builtin_amdgcn_global_load_lds((AS1 void*)ga, (AS3 void*)la, 16, 0, 0);
            __builtin_amdgcn_global_load_lds((AS1 void*)gb, (AS3 void*)lb, 16, 0, 0);
        }
    };

    f32x4 acc[4][4] = {};
    stage(0, 0);
    int cur = 0;
    for (int k0 = 0; k0 < K; k0 += 32) {
        __syncthreads();                        // drains vmcnt: buf[cur] ready; prev reads done
        if (k0 + 32 < K) stage(k0 + 32, cur ^ 1);  // latency hidden behind compute below
        const unsigned short* Ab = As[cur];
        const unsigned short* Bb = Bs[cur];
        bf16x8 af[4], bfg[4];
#pragma unroll
        for (int i = 0; i < 4; ++i)
            af[i] = *(const bf16x8*)(Ab + (rowA_f + i * 16) * 32 + kq);
#pragma unroll
        for (int j = 0; j < 4; ++j)
            bfg[j] = *(const bf16x8*)(Bb + (rowB_f + j * 16) * 32 + kq);
#pragma unroll
        for (int i = 0; i < 4; ++i)
#pragma unroll
            for (int j = 0; j < 4; ++j)
                acc[i][j] = __builtin_amdgcn_mfma_f32_16x16x32_bf16(af[i], bfg[j], acc[i][j], 0, 0, 0);
        cur ^= 1;
    }

    // C/D layout: col=lane&15, row=(lane>>4)*4+r  [m89]
    const int cn = lane & 15;
    const int rbase = (lane >> 4) * 4;
#pragma unroll
    for (int i = 0; i < 4; ++i) {
#pragma unroll
        for (int j = 0; j < 4; ++j) {
            int n = n0 + wn + j * 16 + cn;
            float bv = bias[n];
            int mb = m0 + wm + i * 16 + rbase;
#pragma unroll
            for (int r = 0; r < 4; ++r) {
                float c = acc[i][j][r] + bv;
                if (GELU_BF16_OUT) {
                    c = gelu_fast(c);
                    ((unsigned short*)Cout)[(size_t)(mb + r) * N + n] = f2bf(c);
                } else {
                    ((float*)Cout)[(size_t)(mb + r) * N + n] = c;
                }
            }
        }
    }
}

// per-row LayerNorm in place, float4. grid rows, block 256
__global__ void ln_rows_kernel(float* __restrict__ x, const float* __restrict__ g,
                               const float* __restrict__ beta) {
    __shared__ float red[32];
    float* p = x + (size_t)blockIdx.x * H;
    int t = threadIdx.x;
    float4 v = *(const float4*)(p + t * 4);
    float s = v.x + v.y + v.z + v.w;
    float mu = block_sum(s, red) * (1.0f / H);
    float4 d = { v.x - mu, v.y - mu, v.z - mu, v.w - mu };
    float d2 = d.x * d.x + d.y * d.y + d.z * d.z + d.w * d.w;
    float var = block_sum(d2, red) * (1.0f / H);
    float inv = rsqrtf(var + LN_EPS);
    float4 gg = *(const float4*)(g + t * 4);
    float4 bb = *(const float4*)(beta + t * 4);
    float4 o = { d.x * inv * gg.x + bb.x, d.y * inv * gg.y + bb.y,
                 d.z * inv * gg.z + bb.z, d.w * inv * gg.w + bb.w };
    *(float4*)(p + t * 4) = o;
}

// ---------- launch ----------

extern "C" void kernel_launch(void* const* d_in, const int* in_sizes, int n_in,
                              void* d_out, int out_size, void* d_ws, size_t ws_size,
                              hipStream_t stream) {
    const float* hs     = (const float*)d_in[0];
    const float* ent    = (const float*)d_in[1];
    const float* ee_w1  = (const float*)d_in[2];
    const float* ee_b1  = (const float*)d_in[3];
    const float* ee_w2  = (const float*)d_in[4];
    const float* ee_b2  = (const float*)d_in[5];
    const float* ee_g   = (const float*)d_in[6];
    const float* ee_be  = (const float*)d_in[7];
    const float* re_w1  = (const float*)d_in[8];
    const float* re_b1  = (const float*)d_in[9];
    const float* re_w2  = (const float*)d_in[10];
    const float* re_b2  = (const float*)d_in[11];
    const float* re_g   = (const float*)d_in[12];
    const float* re_be  = (const float*)d_in[13];
    const float* rn_w1  = (const float*)d_in[14];
    const float* rn_b1  = (const float*)d_in[15];
    const float* rn_w2  = (const float*)d_in[16];
    const float* rn_b2  = (const float*)d_in[17];
    const float* rn_g   = (const float*)d_in[18];
    const float* rn_be  = (const float*)d_in[19];
    const float* vn_w1  = (const float*)d_in[20];
    const float* vn_b1  = (const float*)d_in[21];
    const float* vn_w2  = (const float*)d_in[22];
    const float* vn_b2  = (const float*)d_in[23];

    float* out = (float*)d_out;
    float* ef   = out;
    float* rel  = ef + (size_t)BATCH * SEQ * H;
    float* retr = rel + BATCH * H;
    float* sims = retr + BATCH * TOPK * H;
    float* tidx = sims + BATCH * N_ENT;
    float* ro   = tidx + BATCH * TOPK;
    float* vs   = ro + BATCH * H;

    float* ws = (float*)d_ws;
    size_t o = 0;
    float* pooled = ws + o; o += 8192;
    int*   idx_i  = (int*)(ws + o); o += 64;
    float* xin    = ws + o; o += 8 * 3 * H;
    float* h1r    = ws + o; o += 8 * H;
    float* relp   = ws + o; o += 8 * H;
    float* h1n    = ws + o; o += 8 * 2 * H;
    float* rop    = ws + o; o += 8 * H;
    float* h1v    = ws + o; o += 8 * 512;
    float* part   = ws + o; o += 8 * 32 * H;   // pooling partials (1 MB)
    unsigned short* w1t = (unsigned short*)(ws + o); o += (2048 * 1024) / 2;
    unsigned short* w2t = (unsigned short*)(ws + o); o += (2048 * 1024) / 2;
    unsigned short* hsb = (unsigned short*)(ws + o);

    long long avail = (long long)(ws_size / 4) - (long long)o;
    int chunk = (int)(avail / 1536);  // per row: 512 (hsb) + 1024 (mid) floats
    chunk &= ~127;
    int total = BATCH * SEQ;
    if (chunk > total) chunk = total;
    if (chunk < 128) chunk = 128;
    bool full = (chunk >= total);
    unsigned short* midb = hsb + (size_t)chunk * H;

    // weight prep
    transpose_bf_kernel<<<dim3(2048 / 32, 1024 / 32), 256, 0, stream>>>(ee_w1, w1t, 1024, 2048);
    transpose_bf_kernel<<<dim3(1024 / 32, 2048 / 32), 256, 0, stream>>>(ee_w2, w2t, 2048, 1024);

    // pooling (+ hs->bf16 fused when ws fits all rows)
    pool1_kernel<<<dim3(32, BATCH), 256, 0, stream>>>(hs, part, full ? hsb : nullptr);
    pool2_kernel<<<dim3(4, BATCH), 256, 0, stream>>>(part, pooled);

    // relation encoder
    fc_kernel<1024, 1><<<16, 256, 0, stream>>>(pooled, re_w1, re_b1, 1024, h1r);
    fc_kernel<1024, 0><<<16, 256, 0, stream>>>(h1r, re_w2, re_b2, 1024, relp);
    ln_vec_kernel<<<BATCH, 1024, 0, stream>>>(relp, re_g, re_be, rel);

    sim_kernel<<<250, 256, 0, stream>>>(rel, ent, sims);
    topk_kernel<<<BATCH, 256, 0, stream>>>(sims, tidx, idx_i);
    gather_concat_kernel<<<BATCH, 1024, 0, stream>>>(ent, idx_i, rel, pooled, retr, xin);

    // reasoning network
    fc_kernel<3072, 1><<<32, 256, 0, stream>>>(xin, rn_w1, rn_b1, 2048, h1n);
    fc_kernel<2048, 0><<<16, 256, 0, stream>>>(h1n, rn_w2, rn_b2, 1024, rop);
    ln_vec_kernel<<<BATCH, 1024, 0, stream>>>(rop, rn_g, rn_be, ro);

    // validation network
    fc_kernel<1024, 1><<<8, 256, 0, stream>>>(ro, vn_w1, vn_b1, 512, h1v);
    vn_final_kernel<<<BATCH, 512, 0, stream>>>(h1v, vn_w2, vn_b2, vs);

    // entity encoder (bf16 MFMA)
    for (int r0 = 0; r0 < total; r0 += chunk) {
        int m = total - r0;
        if (m > chunk) m = chunk;
        if (!full) {
            int nconv = m * H;
            f2bf_kernel<<<(nconv / 4 + 255) / 256, 256, 0, stream>>>(hs + (size_t)r0 * H, hsb, nconv);
        }
        unsigned short* a1 = full ? (hsb + (size_t)r0 * H) : hsb;
        gemm_mfma<1><<<(m / 128) * (2048 / 128), 256, 0, stream>>>(a1, w1t, ee_b1, midb,
                                                                   m, 2048, 1024);
        gemm_mfma<0><<<(m / 128) * (1024 / 128), 256, 0, stream>>>(midb, w2t, ee_b2,
                                                                   ef + (size_t)r0 * H,
                                                                   m, 1024, 2048);
    }
    ln_rows_kernel<<<total, 256, 0, stream>>>(ef, ee_g, ee_be);
}

// Round 5
// 577.627 us; speedup vs baseline: 1.3045x; 1.3045x over previous
//
#include <hip/hip_runtime.h>
#include <math.h>

#define H 1024
#define SEQ 2048
#define BATCH 8
#define N_ENT 1000
#define TOPK 5
#define LN_EPS 1e-5f

using bf16x8 = __attribute__((ext_vector_type(8))) __bf16;
using f32x4  = __attribute__((ext_vector_type(4))) float;
#define AS1 __attribute__((address_space(1)))
#define AS3 __attribute__((address_space(3)))

// ---------- helpers ----------

// fast erf-GELU: Abramowitz-Stegun 7.1.26, |erf err| <= 1.5e-7, hw rcp/exp2
__device__ __forceinline__ float gelu_fast(float x) {
    float z = fabsf(x) * 0.70710678118654752440f;
    float t = __builtin_amdgcn_rcpf(fmaf(0.3275911f, z, 1.0f));
    float p = fmaf(fmaf(fmaf(fmaf(1.061405429f, t, -1.453152027f), t, 1.421413741f),
                        t, -0.284496736f), t, 0.254829592f) * t;
    float e = __builtin_amdgcn_exp2f(-z * z * 1.44269504088896f);
    float erfz = fmaf(-p, e, 1.0f);
    float s = copysignf(erfz, x);
    return 0.5f * x * (1.0f + s);
}

__device__ __forceinline__ float sigmoidf_(float x) {
    return 1.0f / (1.0f + expf(-x));
}

__device__ __forceinline__ unsigned short f2bf(float f) {
    unsigned int u = __float_as_uint(f);
    unsigned int r = (u + 0x7fffu + ((u >> 16) & 1u)) >> 16;  // RNE
    return (unsigned short)r;
}

__device__ float block_sum(float v, float* red) {
    for (int off = 32; off > 0; off >>= 1) v += __shfl_down(v, off, 64);
    int wid = threadIdx.x >> 6;
    int lane = threadIdx.x & 63;
    int nw = blockDim.x >> 6;
    if (lane == 0) red[wid] = v;
    __syncthreads();
    if (threadIdx.x == 0) {
        float s = 0.f;
        for (int i = 0; i < nw; ++i) s += red[i];
        red[0] = s;
    }
    __syncthreads();
    float r = red[0];
    __syncthreads();
    return r;
}

// ---------- conversion kernels ----------

__global__ void f2bf_kernel(const float* __restrict__ in, unsigned short* __restrict__ out, int n) {
    int i = (blockIdx.x * blockDim.x + threadIdx.x) * 4;
    if (i >= n) return;
    float4 v = *(const float4*)(in + i);
    ushort4 o;
    o.x = f2bf(v.x); o.y = f2bf(v.y); o.z = f2bf(v.z); o.w = f2bf(v.w);
    *(ushort4*)(out + i) = o;
}

// in [R][C] fp32 -> out [C][R] bf16
__global__ void transpose_bf_kernel(const float* __restrict__ in, unsigned short* __restrict__ out,
                                    int R, int C) {
    __shared__ float tile[32][33];
    int c0 = blockIdx.x * 32, r0 = blockIdx.y * 32;
    int tx = threadIdx.x & 31, ty = threadIdx.x >> 5;
#pragma unroll
    for (int i = 0; i < 32; i += 8)
        tile[ty + i][tx] = in[(size_t)(r0 + ty + i) * C + c0 + tx];
    __syncthreads();
#pragma unroll
    for (int i = 0; i < 32; i += 8)
        out[(size_t)(c0 + ty + i) * R + r0 + tx] = f2bf(tile[tx][ty + i]);
}

// ---------- pooling (2-phase) + fused hs->bf16 ----------

// grid (32, 8), block 256; float4 per thread per row
__global__ void pool1_kernel(const float* __restrict__ hs, float* __restrict__ part,
                             unsigned short* __restrict__ hsb) {
    int sc = blockIdx.x, b = blockIdx.y, t = threadIdx.x;
    size_t rowbase = (size_t)b * SEQ + sc * 64;
    const float* p = hs + rowbase * H + t * 4;
    float4 a = {0.f, 0.f, 0.f, 0.f};
    for (int s = 0; s < 64; ++s) {
        float4 v = *(const float4*)(p + (size_t)s * H);
        a.x += v.x; a.y += v.y; a.z += v.z; a.w += v.w;
        if (hsb) {
            ushort4 o;
            o.x = f2bf(v.x); o.y = f2bf(v.y); o.z = f2bf(v.z); o.w = f2bf(v.w);
            *(ushort4*)(hsb + (rowbase + s) * H + t * 4) = o;
        }
    }
    *(float4*)(part + ((size_t)b * 32 + sc) * H + t * 4) = a;
}

// grid 8, block 256; float4 cols per thread
__global__ void pool2_kernel(const float* __restrict__ part, float* __restrict__ pooled) {
    int b = blockIdx.x, t = threadIdx.x;
    float4 s = {0.f, 0.f, 0.f, 0.f};
    for (int sc = 0; sc < 32; ++sc) {
        float4 v = *(const float4*)(part + ((size_t)b * 32 + sc) * H + t * 4);
        s.x += v.x; s.y += v.y; s.z += v.z; s.w += v.w;
    }
    float4 o = {s.x * (1.0f / SEQ), s.y * (1.0f / SEQ), s.z * (1.0f / SEQ), s.w * (1.0f / SEQ)};
    *(float4*)(pooled + (size_t)b * H + t * 4) = o;
}

// ---------- small MLP path: k-split partial + reduce ----------

// partial[ks][b][j] = sum_{k in ks-range} X[b][k] * W[k][j]
// grid (N/256, K/KRANGE), block 256
template <int KRANGE>
__global__ void mlp_partial_kernel(const float* __restrict__ X, int ldx,
                                   const float* __restrict__ W, int N,
                                   float* __restrict__ part) {
    __shared__ float xs[8][KRANGE];
    int jb = blockIdx.x, ks = blockIdx.y, t = threadIdx.x;
    int k0 = ks * KRANGE;
    for (int i = t; i < 8 * KRANGE; i += 256) {
        int b = i / KRANGE, k = i % KRANGE;
        xs[b][k] = X[(size_t)b * ldx + k0 + k];
    }
    __syncthreads();
    int j = jb * 256 + t;
    float acc[8] = {};
    for (int k = 0; k < KRANGE; ++k) {
        float w = W[(size_t)(k0 + k) * N + j];
#pragma unroll
        for (int b = 0; b < 8; ++b) acc[b] = fmaf(xs[b][k], w, acc[b]);
    }
#pragma unroll
    for (int b = 0; b < 8; ++b) part[((size_t)ks * 8 + b) * N + j] = acc[b];
}

__global__ void mlp_reduce_gelu_kernel(const float* __restrict__ part, const float* __restrict__ bias,
                                       float* __restrict__ out, int N, int nks) {
    int b = blockIdx.y;
    int j = blockIdx.x * 256 + threadIdx.x;
    float s = bias[j];
    for (int ks = 0; ks < nks; ++ks) s += part[((size_t)ks * 8 + b) * N + j];
    out[(size_t)b * N + j] = gelu_fast(s);
}

__global__ void mlp_reduce_ln_kernel(const float* __restrict__ part, const float* __restrict__ bias,
                                     const float* __restrict__ g, const float* __restrict__ be,
                                     float* __restrict__ out, int nks) {
    __shared__ float red[32];
    int b = blockIdx.x, t = threadIdx.x;
    float s = bias[t];
    for (int ks = 0; ks < nks; ++ks) s += part[((size_t)ks * 8 + b) * H + t];
    float mu = block_sum(s, red) * (1.0f / H);
    float d = s - mu;
    float var = block_sum(d * d, red) * (1.0f / H);
    out[(size_t)b * H + t] = d * rsqrtf(var + LN_EPS) * g[t] + be[t];
}

// ---------- sims / topk / gather+concat / validation tail ----------

__global__ void sim_kernel(const float* __restrict__ rel, const float* __restrict__ ent,
                           float* __restrict__ sims) {
    __shared__ float rl[8 * H];
    int t = threadIdx.x;
    for (int i = t; i < 8 * H; i += 256) rl[i] = rel[i];
    __syncthreads();
    int e = blockIdx.x * 4 + (t >> 6);
    int lane = t & 63;
    float ev[16];
    const float* ep = ent + (size_t)e * H;
#pragma unroll
    for (int i = 0; i < 16; ++i) ev[i] = ep[lane + i * 64];
#pragma unroll
    for (int b = 0; b < 8; ++b) {
        float a = 0.f;
#pragma unroll
        for (int i = 0; i < 16; ++i) a = fmaf(ev[i], rl[b * H + lane + i * 64], a);
        for (int off = 32; off > 0; off >>= 1) a += __shfl_down(a, off, 64);
        if (lane == 0) sims[b * N_ENT + e] = a;
    }
}

__global__ void topk_kernel(const float* __restrict__ sims, float* __restrict__ out_idx_f,
                            int* __restrict__ idx_i) {
    __shared__ float v[1024];
    __shared__ float rv[4];
    __shared__ int ri[4];
    int b = blockIdx.x, t = threadIdx.x;
    for (int i = t; i < 1024; i += 256) v[i] = (i < N_ENT) ? sims[b * N_ENT + i] : -INFINITY;
    __syncthreads();
    for (int k = 0; k < TOPK; ++k) {
        float best = -INFINITY;
        int bi = 0x7fffffff;
        for (int i = t; i < 1024; i += 256) {
            float x = v[i];
            if (x > best || (x == best && i < bi)) { best = x; bi = i; }
        }
        for (int off = 32; off > 0; off >>= 1) {
            float ov = __shfl_down(best, off, 64);
            int oi = __shfl_down(bi, off, 64);
            if (ov > best || (ov == best && oi < bi)) { best = ov; bi = oi; }
        }
        if ((t & 63) == 0) { rv[t >> 6] = best; ri[t >> 6] = bi; }
        __syncthreads();
        if (t == 0) {
            for (int w = 1; w < 4; ++w)
                if (rv[w] > rv[0] || (rv[w] == rv[0] && ri[w] < ri[0])) { rv[0] = rv[w]; ri[0] = ri[w]; }
            int sel = ri[0];
            out_idx_f[b * TOPK + k] = (float)sel;
            idx_i[b * TOPK + k] = sel;
            v[sel] = -INFINITY;
        }
        __syncthreads();
    }
}

__global__ void gather_concat_kernel(const float* __restrict__ ent, const int* __restrict__ idx,
                                     const float* __restrict__ rel, const float* __restrict__ pooled,
                                     float* __restrict__ retrieved, float* __restrict__ xin) {
    int b = blockIdx.x, h = threadIdx.x;
    float acc = 0.f;
    for (int k = 0; k < TOPK; ++k) {
        float v = ent[(size_t)idx[b * TOPK + k] * H + h];
        retrieved[((size_t)b * TOPK + k) * H + h] = v;
        acc += v;
    }
    float* xb = xin + (size_t)b * 3 * H;
    xb[h] = acc * (1.0f / TOPK);
    xb[H + h] = rel[b * H + h];
    xb[2 * H + h] = pooled[b * H + h];
}

// partial sums of vn layer1 in, gelu+dot+sigmoid.  grid 8, block 512
__global__ void vn_final_kernel(const float* __restrict__ part, const float* __restrict__ b1,
                                const float* __restrict__ w2, const float* __restrict__ b2,
                                float* __restrict__ vs, int nks) {
    __shared__ float red[32];
    int b = blockIdx.x, t = threadIdx.x;
    float s = b1[t];
    for (int ks = 0; ks < nks; ++ks) s += part[((size_t)ks * 8 + b) * 512 + t];
    float c = gelu_fast(s) * w2[t];
    float tot = block_sum(c, red);
    if (t == 0) vs[b] = sigmoidf_(tot + b2[0]);
}

// ---------- bf16 MFMA GEMM ----------
// 128x128 tile, BK=32, double-buffered LDS (single barrier/iter),
// XCD-aligned group swizzle (GROUP_M=8).
template <int GELU_BF16_OUT>
__global__ __launch_bounds__(256) void gemm_mfma(const unsigned short* __restrict__ A,
                                                 const unsigned short* __restrict__ Bt,
                                                 const float* __restrict__ bias,
                                                 void* __restrict__ Cout,
                                                 int M, int N, int K) {
    __shared__ __align__(16) unsigned short As[2][128 * 32];
    __shared__ __align__(16) unsigned short Bs[2][128 * 32];
    const int tid = threadIdx.x;
    const int lane = tid & 63;

    const int Mp = M >> 7, Np = N >> 7;
    const int GM = 8;
    int per_group = GM * Np;
    int group = blockIdx.x / per_group;
    int rem = blockIdx.x - group * per_group;
    int gbase = group * GM;
    int gm = Mp - gbase; if (gm > GM) gm = GM;
    const int m0 = (gbase + rem % gm) * 128;
    const int n0 = (rem / gm) * 128;

    const int wave = tid >> 6;
    const int wm = (wave >> 1) * 64, wn = (wave & 1) * 64;
    const int rowA_f = wm + (lane & 15);
    const int rowB_f = wn + (lane & 15);
    const int kq = (lane >> 4) * 8;

    auto stage = [&](int kbase, int buf) {
#pragma unroll
        for (int r = 0; r < 2; ++r) {
            int e = (r * 256 + tid) * 8;
            int row = e >> 5, kk = e & 31;
            const unsigned short* ga = A + (size_t)(m0 + row) * K + kbase + kk;
            const unsigned short* gb = Bt + (size_t)(n0 + row) * K + kbase + kk;
            unsigned short* la = &As[buf][(size_t)(r * 256 + (tid & ~63)) * 8];
            unsigned short* lb = &Bs[buf][(size_t)(r * 256 + (tid & ~63)) * 8];
            __builtin_amdgcn_global_load_lds((AS1 void*)ga, (AS3 void*)la, 16, 0, 0);
            __builtin_amdgcn_global_load_lds((AS1 void*)gb, (AS3 void*)lb, 16, 0, 0);
        }
    };

    f32x4 acc[4][4] = {};
    stage(0, 0);
    int cur = 0;
    for (int k0 = 0; k0 < K; k0 += 32) {
        __syncthreads();                           // buf[cur] ready; prev reads done
        if (k0 + 32 < K) stage(k0 + 32, cur ^ 1);  // prefetch hidden behind compute
        const unsigned short* Ab = As[cur];
        const unsigned short* Bb = Bs[cur];
        bf16x8 af[4], bfg[4];
#pragma unroll
        for (int i = 0; i < 4; ++i)
            af[i] = *(const bf16x8*)(Ab + (rowA_f + i * 16) * 32 + kq);
#pragma unroll
        for (int j = 0; j < 4; ++j)
            bfg[j] = *(const bf16x8*)(Bb + (rowB_f + j * 16) * 32 + kq);
#pragma unroll
        for (int i = 0; i < 4; ++i)
#pragma unroll
            for (int j = 0; j < 4; ++j)
                acc[i][j] = __builtin_amdgcn_mfma_f32_16x16x32_bf16(af[i], bfg[j], acc[i][j], 0, 0, 0);
        cur ^= 1;
    }

    // C/D layout: col=lane&15, row=(lane>>4)*4+r  [m89]
    const int cn = lane & 15;
    const int rbase = (lane >> 4) * 4;
#pragma unroll
    for (int i = 0; i < 4; ++i) {
#pragma unroll
        for (int j = 0; j < 4; ++j) {
            int n = n0 + wn + j * 16 + cn;
            float bv = bias[n];
            int mb = m0 + wm + i * 16 + rbase;
#pragma unroll
            for (int r = 0; r < 4; ++r) {
                float c = acc[i][j][r] + bv;
                if (GELU_BF16_OUT) {
                    c = gelu_fast(c);
                    ((unsigned short*)Cout)[(size_t)(mb + r) * N + n] = f2bf(c);
                } else {
                    ((float*)Cout)[(size_t)(mb + r) * N + n] = c;
                }
            }
        }
    }
}

// per-row LayerNorm in place, float4. grid rows, block 256
__global__ void ln_rows_kernel(float* __restrict__ x, const float* __restrict__ g,
                               const float* __restrict__ beta) {
    __shared__ float red[32];
    float* p = x + (size_t)blockIdx.x * H;
    int t = threadIdx.x;
    float4 v = *(const float4*)(p + t * 4);
    float s = v.x + v.y + v.z + v.w;
    float mu = block_sum(s, red) * (1.0f / H);
    float4 d = { v.x - mu, v.y - mu, v.z - mu, v.w - mu };
    float d2 = d.x * d.x + d.y * d.y + d.z * d.z + d.w * d.w;
    float var = block_sum(d2, red) * (1.0f / H);
    float inv = rsqrtf(var + LN_EPS);
    float4 gg = *(const float4*)(g + t * 4);
    float4 bb = *(const float4*)(beta + t * 4);
    float4 o = { d.x * inv * gg.x + bb.x, d.y * inv * gg.y + bb.y,
                 d.z * inv * gg.z + bb.z, d.w * inv * gg.w + bb.w };
    *(float4*)(p + t * 4) = o;
}

// ---------- launch ----------

extern "C" void kernel_launch(void* const* d_in, const int* in_sizes, int n_in,
                              void* d_out, int out_size, void* d_ws, size_t ws_size,
                              hipStream_t stream) {
    const float* hs     = (const float*)d_in[0];
    const float* ent    = (const float*)d_in[1];
    const float* ee_w1  = (const float*)d_in[2];
    const float* ee_b1  = (const float*)d_in[3];
    const float* ee_w2  = (const float*)d_in[4];
    const float* ee_b2  = (const float*)d_in[5];
    const float* ee_g   = (const float*)d_in[6];
    const float* ee_be  = (const float*)d_in[7];
    const float* re_w1  = (const float*)d_in[8];
    const float* re_b1  = (const float*)d_in[9];
    const float* re_w2  = (const float*)d_in[10];
    const float* re_b2  = (const float*)d_in[11];
    const float* re_g   = (const float*)d_in[12];
    const float* re_be  = (const float*)d_in[13];
    const float* rn_w1  = (const float*)d_in[14];
    const float* rn_b1  = (const float*)d_in[15];
    const float* rn_w2  = (const float*)d_in[16];
    const float* rn_b2  = (const float*)d_in[17];
    const float* rn_g   = (const float*)d_in[18];
    const float* rn_be  = (const float*)d_in[19];
    const float* vn_w1  = (const float*)d_in[20];
    const float* vn_b1  = (const float*)d_in[21];
    const float* vn_w2  = (const float*)d_in[22];
    const float* vn_b2  = (const float*)d_in[23];

    float* out = (float*)d_out;
    float* ef   = out;
    float* rel  = ef + (size_t)BATCH * SEQ * H;
    float* retr = rel + BATCH * H;
    float* sims = retr + BATCH * TOPK * H;
    float* tidx = sims + BATCH * N_ENT;
    float* ro   = tidx + BATCH * TOPK;
    float* vs   = ro + BATCH * H;

    float* ws = (float*)d_ws;
    size_t o = 0;
    float* pooled = ws + o; o += 8192;
    int*   idx_i  = (int*)(ws + o); o += 64;
    float* xin    = ws + o; o += 8 * 3 * H;
    float* h1r    = ws + o; o += 8 * H;
    float* h1n    = ws + o; o += 8 * 2 * H;
    float* part   = ws + o; o += 24 * 8 * 2048;   // 393216 floats, reused by all stages
    unsigned short* w1t = (unsigned short*)(ws + o); o += (2048 * 1024) / 2;
    unsigned short* w2t = (unsigned short*)(ws + o); o += (2048 * 1024) / 2;
    unsigned short* hsb = (unsigned short*)(ws + o);

    long long avail = (long long)(ws_size / 4) - (long long)o;
    int chunk = (int)(avail / 1536);  // per row: 512 (hsb) + 1024 (mid) floats
    chunk &= ~127;
    int total = BATCH * SEQ;
    if (chunk > total) chunk = total;
    if (chunk < 128) chunk = 128;
    bool full = (chunk >= total);
    unsigned short* midb = hsb + (size_t)chunk * H;

    // weight prep
    transpose_bf_kernel<<<dim3(2048 / 32, 1024 / 32), 256, 0, stream>>>(ee_w1, w1t, 1024, 2048);
    transpose_bf_kernel<<<dim3(1024 / 32, 2048 / 32), 256, 0, stream>>>(ee_w2, w2t, 2048, 1024);

    // pooling (+ hs->bf16 fused when ws fits all rows)
    pool1_kernel<<<dim3(32, BATCH), 256, 0, stream>>>(hs, part, full ? hsb : nullptr);
    pool2_kernel<<<BATCH, 256, 0, stream>>>(part, pooled);

    // relation encoder
    mlp_partial_kernel<64><<<dim3(4, 16), 256, 0, stream>>>(pooled, H, re_w1, H, part);
    mlp_reduce_gelu_kernel<<<dim3(4, 8), 256, 0, stream>>>(part, re_b1, h1r, H, 16);
    mlp_partial_kernel<64><<<dim3(4, 16), 256, 0, stream>>>(h1r, H, re_w2, H, part);
    mlp_reduce_ln_kernel<<<BATCH, 1024, 0, stream>>>(part, re_b2, re_g, re_be, rel, 16);

    sim_kernel<<<250, 256, 0, stream>>>(rel, ent, sims);
    topk_kernel<<<BATCH, 256, 0, stream>>>(sims, tidx, idx_i);
    gather_concat_kernel<<<BATCH, 1024, 0, stream>>>(ent, idx_i, rel, pooled, retr, xin);

    // reasoning network
    mlp_partial_kernel<128><<<dim3(8, 24), 256, 0, stream>>>(xin, 3 * H, rn_w1, 2 * H, part);
    mlp_reduce_gelu_kernel<<<dim3(8, 8), 256, 0, stream>>>(part, rn_b1, h1n, 2 * H, 24);
    mlp_partial_kernel<128><<<dim3(4, 16), 256, 0, stream>>>(h1n, 2 * H, rn_w2, H, part);
    mlp_reduce_ln_kernel<<<BATCH, 1024, 0, stream>>>(part, rn_b2, rn_g, rn_be, ro, 16);

    // validation network
    mlp_partial_kernel<128><<<dim3(2, 8), 256, 0, stream>>>(ro, H, vn_w1, 512, part);
    vn_final_kernel<<<BATCH, 512, 0, stream>>>(part, vn_b1, vn_w2, vn_b2, vs, 8);

    // entity encoder (bf16 MFMA)
    for (int r0 = 0; r0 < total; r0 += chunk) {
        int m = total - r0;
        if (m > chunk) m = chunk;
        if (!full) {
            int nconv = m * H;
            f2bf_kernel<<<(nconv / 4 + 255) / 256, 256, 0, stream>>>(hs + (size_t)r0 * H, hsb, nconv);
        }
        unsigned short* a1 = full ? (hsb + (size_t)r0 * H) : hsb;
        gemm_mfma<1><<<(m / 128) * (2048 / 128), 256, 0, stream>>>(a1, w1t, ee_b1, midb,
                                                                   m, 2048, 1024);
        gemm_mfma<0><<<(m / 128) * (1024 / 128), 256, 0, stream>>>(midb, w2t, ee_b2,
                                                                   ef + (size_t)r0 * H,
                                                                   m, 1024, 2048);
    }
    ln_rows_kernel<<<total, 256, 0, stream>>>(ef, ee_g, ee_be);
}